// Round 3
// baseline (102.470 us; speedup 1.0000x reference)
//
#include <hip/hip_runtime.h>
#include <cstdint>
#include <cstddef>

typedef __attribute__((ext_vector_type(4))) float f32x4;
typedef __attribute__((ext_vector_type(8))) short bf16x8;
typedef __attribute__((ext_vector_type(4))) short bf16x4;
typedef __attribute__((ext_vector_type(2))) short bf16x2;

#define DEVI static __device__ __forceinline__

DEVI short f2bf(float f){
  union { float f; uint32_t u; } v; v.f = f;
  uint32_t r = v.u + 0x7FFFu + ((v.u >> 16) & 1u);
  return (short)(r >> 16);
}
DEVI float bf2f(short h){
  union { uint32_t u; float f; } v; v.u = ((uint32_t)(uint16_t)h) << 16;
  return v.f;
}
DEVI float eluf(float x){ return x > 0.f ? x : (__expf(x) - 1.f); }
DEVI float sigm(float x){ return 1.f / (1.f + __expf(-x)); }

static constexpr int NPIX = 8 * 1024;   // B*S pixels

// ---- workspace layout (bytes) ----
static constexpr size_t SZ_W   = (size_t)983040 * 2;        // 3 branches x (w1 65536 + w2 131072 + wn 131072) bf16
static constexpr size_t SZ_ACT = (size_t)NPIX * 256 * 2;
static constexpr size_t OFF_W   = 0;
// (gaps kept identical to the previously-validated layout; only W and TOK are used now)
static constexpr size_t OFF_TOK = OFF_W + SZ_W + 8*SZ_ACT;  // 3 x (B,512,1024) bf16 channel-major

// swizzled LDS offset (row stride 256 shorts); XOR acts on bits 3..5 of col
DEVI int swz(int row, int col){ return row*256 + (col ^ ((row & 7) << 3)); }
// swizzled LDS offset for W tiles (row stride 64 shorts)
DEVI int swzW(int row, int col){ return row*64 + (col ^ ((row & 7) << 3)); }

// ---------------- weight fp32 -> bf16 ----------------
__global__ void k_prep(const float* __restrict__ w1q, const float* __restrict__ w2q, const float* __restrict__ wnq,
                       const float* __restrict__ w1k, const float* __restrict__ w2k, const float* __restrict__ wnk,
                       const float* __restrict__ w1v, const float* __restrict__ w2v, const float* __restrict__ wnv,
                       short* __restrict__ dst)
{
  const float* s1[3] = {w1q, w1k, w1v};
  const float* s2[3] = {w2q, w2k, w2v};
  const float* s3[3] = {wnq, wnk, wnv};
  const int stride = gridDim.x * blockDim.x;
  for (int i = blockIdx.x * blockDim.x + threadIdx.x; i < 983040; i += stride){
    int br = i / 327680;
    int r  = i - br * 327680;
    float v;
    if (r < 65536)        v = s1[br][r];
    else if (r < 196608)  v = s2[br][r - 65536];
    else                  v = s3[br][r - 196608];
    dst[i] = f2bf(v);
  }
}

// ---------------- fused branch kernel ----------------
// One block = one 64-token tile x one branch z. The whole chain
//   ex = elu(x); h1 = elu(W1@ex+b1); [a;g] = W2@h1+b2; gr = x + a*sig(g); tok = Wn@gr+bn
// reduces over channels only, so a token-column tile is self-contained.
// LDS: sEX [64 n][256 k] (reused as sGR), sH1 [64 n][256 m] (phase-E temp first),
//      sW [128 m][64 k] weight staging. 80 KB -> 2 blocks/CU.
// Waves split n 16-wide (n_local = w*16 + li); m handled by per-pass loops.
__global__ void k_branch(const short* __restrict__ wsW,
                         const float* __restrict__ query, const float* __restrict__ key,
                         const float* __restrict__ b1q, const float* __restrict__ b1k, const float* __restrict__ b1v,
                         const float* __restrict__ b2q, const float* __restrict__ b2k, const float* __restrict__ b2v,
                         const float* __restrict__ bnq, const float* __restrict__ bnk, const float* __restrict__ bnv,
                         short* __restrict__ tok)
{
  __shared__ short sEX[64*256];   // ex, later gr  (32 KB)
  __shared__ short sH1[64*256];   // phase-E temp [256][64], then h1 [n][m]  (32 KB)
  __shared__ short sW [128*64];   // weight tile  (16 KB)

  const int z = blockIdx.y;
  const int b = blockIdx.x >> 4;
  const int sp0 = (blockIdx.x & 15) * 64;
  const float* xin = (z == 0) ? query : key;
  const float* b1z = (z == 0) ? b1q : ((z == 1) ? b1k : b1v);
  const float* b2z = (z == 0) ? b2q : ((z == 1) ? b2k : b2v);
  const float* bnz = (z == 0) ? bnq : ((z == 1) ? bnk : bnv);
  const short* W1 = wsW + (size_t)z * 327680;
  const short* W2 = W1 + 65536;
  const short* Wn = W1 + 196608;
  short* tokz = tok + (size_t)z * NPIX * 512;

  const int tid = threadIdx.x, w = tid >> 6, g = (tid >> 4) & 3, li = tid & 15;
  const int nl = w*16 + li;            // this lane's token (column) within the tile
  const int sp = sp0 + nl;

  // ---- phase E: x -> elu -> bf16, transposed to sEX[n][c] ----
  #pragma unroll
  for (int i = 0; i < 16; i++){
    int idx = tid + i*256;             // c = idx>>4, u = idx&15 (float4 along sp)
    int c = idx >> 4, u = idx & 15;
    f32x4 v4 = *(const f32x4*)(xin + ((size_t)(b*256 + c))*1024 + sp0 + u*4);
    bf16x4 pk;
    #pragma unroll
    for (int r = 0; r < 4; r++) pk[r] = f2bf(eluf(v4[r]));
    *(bf16x4*)(sH1 + c*64 + u*4) = pk; // temp [c][sp_local], plain
  }
  __syncthreads();
  #pragma unroll
  for (int i = 0; i < 8; i++){
    int idx = tid + i*256;             // sp_ = idx&63, cb = idx>>6
    int sp_ = idx & 63, cb = idx >> 6;
    bf16x8 pk;
    #pragma unroll
    for (int j = 0; j < 8; j++) pk[j] = sH1[(cb*8 + j)*64 + sp_];
    *(bf16x8*)(sEX + swz(sp_, cb*8)) = pk;
  }
  // (no barrier needed here: first GEMM stage begins with one)

  // ---- GEMM1: h1 = elu(W1 @ ex + b1) -> sH1[n][m] ----
  for (int mp = 0; mp < 4; mp++){
    f32x4 acc[4] = {};
    for (int kb = 0; kb < 4; kb++){
      __syncthreads();
      #pragma unroll
      for (int i = 0; i < 2; i++){
        int s = tid + i*256;           // 512 slots of 8 shorts
        int m = s >> 3, j = s & 7;
        bf16x8 v = *(const bf16x8*)(W1 + (size_t)(mp*64 + m)*256 + kb*64 + j*8);
        *(bf16x8*)(sW + swzW(m, j*8)) = v;
      }
      __syncthreads();
      #pragma unroll
      for (int kk = 0; kk < 2; kk++){
        bf16x8 bfr = *(const bf16x8*)(sEX + swz(nl, kb*64 + kk*32 + g*8));
        #pragma unroll
        for (int mt = 0; mt < 4; mt++){
          bf16x8 afr = *(const bf16x8*)(sW + swzW(mt*16 + li, kk*32 + g*8));
          acc[mt] = __builtin_amdgcn_mfma_f32_16x16x32_bf16(afr, bfr, acc[mt], 0, 0, 0);
        }
      }
    }
    #pragma unroll
    for (int mt = 0; mt < 4; mt++){
      int m0 = mp*64 + mt*16 + g*4;
      bf16x4 pk;
      #pragma unroll
      for (int r = 0; r < 4; r++)
        pk[r] = f2bf(eluf(acc[mt][r] + b1z[m0 + r]));
      *(bf16x4*)(sH1 + swz(nl, m0)) = pk;     // h1 transposed [n][m]
    }
  }

  // ---- GEMM2: [a;g] = W2 @ h1 + b2 ; gr = x + a*sig(g) -> sEX[n][m] ----
  for (int mp = 0; mp < 4; mp++){
    f32x4 acc[2][4] = {};
    for (int kb = 0; kb < 4; kb++){
      __syncthreads();
      #pragma unroll
      for (int i = 0; i < 4; i++){
        int s = tid + i*256;           // 1024 slots: a-half rows 0..63, g-half 64..127
        int mr = s >> 3, j = s & 7;
        int m = mp*64 + (mr & 63) + ((mr >> 6) << 8);
        bf16x8 v = *(const bf16x8*)(W2 + (size_t)m*256 + kb*64 + j*8);
        *(bf16x8*)(sW + swzW(mr, j*8)) = v;
      }
      __syncthreads();
      #pragma unroll
      for (int kk = 0; kk < 2; kk++){
        bf16x8 bfr = *(const bf16x8*)(sH1 + swz(nl, kb*64 + kk*32 + g*8));
        #pragma unroll
        for (int h = 0; h < 2; h++){
          #pragma unroll
          for (int mt = 0; mt < 4; mt++){
            bf16x8 afr = *(const bf16x8*)(sW + swzW(h*64 + mt*16 + li, kk*32 + g*8));
            acc[h][mt] = __builtin_amdgcn_mfma_f32_16x16x32_bf16(afr, bfr, acc[h][mt], 0, 0, 0);
          }
        }
      }
    }
    #pragma unroll
    for (int mt = 0; mt < 4; mt++){
      int m0 = mp*64 + mt*16 + g*4;
      bf16x4 pk;
      #pragma unroll
      for (int r = 0; r < 4; r++){
        float a  = acc[0][mt][r] + b2z[m0 + r];
        float gg = acc[1][mt][r] + b2z[m0 + r + 256];
        float xv = xin[((size_t)(b*256) + m0 + r)*1024 + sp];
        pk[r] = f2bf(xv + a * sigm(gg));
      }
      *(bf16x4*)(sEX + swz(nl, m0)) = pk;     // gr overwrites ex (dead after GEMM1)
    }
  }

  // ---- GEMM3: tok = Wn @ gr + bn -> global channel-major bf16 ----
  for (int mp = 0; mp < 8; mp++){
    f32x4 acc[4] = {};
    for (int kb = 0; kb < 4; kb++){
      __syncthreads();
      #pragma unroll
      for (int i = 0; i < 2; i++){
        int s = tid + i*256;
        int m = s >> 3, j = s & 7;
        bf16x8 v = *(const bf16x8*)(Wn + (size_t)(mp*64 + m)*256 + kb*64 + j*8);
        *(bf16x8*)(sW + swzW(m, j*8)) = v;
      }
      __syncthreads();
      #pragma unroll
      for (int kk = 0; kk < 2; kk++){
        bf16x8 bfr = *(const bf16x8*)(sEX + swz(nl, kb*64 + kk*32 + g*8));
        #pragma unroll
        for (int mt = 0; mt < 4; mt++){
          bf16x8 afr = *(const bf16x8*)(sW + swzW(mt*16 + li, kk*32 + g*8));
          acc[mt] = __builtin_amdgcn_mfma_f32_16x16x32_bf16(afr, bfr, acc[mt], 0, 0, 0);
        }
      }
    }
    #pragma unroll
    for (int mt = 0; mt < 4; mt++){
      #pragma unroll
      for (int r = 0; r < 4; r++){
        int m = mp*64 + mt*16 + g*4 + r;
        tokz[((size_t)(b*512) + m)*1024 + sp] = f2bf(acc[mt][r] + bnz[m]);
      }
    }
  }
}

// ---------------- flash attention ----------------
// tok viewed as (B*1024 tokens, 512 feat) bf16; per (b, head): Q,K,V (1024 x 64).
// Strict causal (key < query), scale 1/sqrt(512), row 0 -> 0.
// Swapped QK^T: S^T = mfma(K, Q^T) so softmax state is lane-local (lane owns q = lane&15).
// Grid = 1024 flat blocks; qt permuted so every stride-256 block family (one CU
// under XCD round-robin) has equal total work (perm stride-4 subsets sum to 30).
__global__ void k_attn(const short* __restrict__ tok, float* __restrict__ out)
{
  const short* qtok = tok;
  const short* ktok = tok + (size_t)NPIX * 512;
  const short* vtok = tok + (size_t)2 * NPIX * 512;
  const int flat = blockIdx.x;
  const int p = flat >> 6;
  const int g4 = p >> 2, r4 = p & 3;
  // perm = [15,14,13,12, 0,1,2,3, 11,10,9,8, 4,5,6,7]
  const int qt = (g4 == 0) ? (15 - r4) : (g4 == 1) ? r4 : (g4 == 2) ? (11 - r4) : (4 + r4);
  const int bh = flat & 63;
  const int b = bh >> 3, nh = bh & 7;
  const int tid = threadIdx.x, lane = tid & 63, w = tid >> 6, g = (tid >> 4) & 3, li = tid & 15;
  const int qrow = qt*64 + w*16 + li;       // this lane's query token
  __shared__ short Kl[64*64];
  __shared__ short Vt[64*64];               // V transposed: [d][k]
  __shared__ short Pl[4][1024];             // per-wave P [16 q][64 k]

  const short* qptr = qtok + ((size_t)(b*1024 + qrow))*512 + nh*64;
  bf16x8 qf0 = *(const bf16x8*)(qptr + g*8);
  bf16x8 qf1 = *(const bf16x8*)(qptr + 32 + g*8);

  f32x4 accO[4] = {};                       // O^T: 4 d-frags x (16d x 16q)
  float mrun = -1e30f, lrun = 0.f;
  const float scale = 0.04419417382415922f; // 1/sqrt(512)
  short* Pw = &Pl[w][0];

  for (int kt = 0; kt <= qt; kt++){
    const int kb = kt * 64;
    __syncthreads();
    #pragma unroll
    for (int it = 0; it < 2; it++){
      int i = tid + it*256;
      int kr = i >> 3, kc = i & 7;
      bf16x8 v = *(const bf16x8*)(ktok + ((size_t)(b*1024 + kb + kr))*512 + nh*64 + kc*8);
      *(bf16x8*)(Kl + ((kr*64 + kc*8) ^ ((kr & 7) << 3))) = v;
    }
    #pragma unroll
    for (int it = 0; it < 2; it++){
      int d0 = w*8 + it*32;                 // d uniform within wave -> conflict-free writes
      bf16x8 v = *(const bf16x8*)(vtok + ((size_t)(b*1024 + kb + lane))*512 + nh*64 + d0);
      #pragma unroll
      for (int j = 0; j < 8; j++){
        int d = d0 + j;
        Vt[(d*64 + lane) ^ ((d & 7) << 3)] = v[j];
      }
    }
    __syncthreads();

    // S^T frags: 4 x (16 keys x 16 q)
    float pv[16];
    float mt_ = -1e30f;
    const bool diag = (kt == qt);
    #pragma unroll
    for (int kf = 0; kf < 4; kf++){
      f32x4 sa = {};
      const int krow = kf*16 + li;
      bf16x8 ka  = *(const bf16x8*)(Kl + ((krow*64 + g*8) ^ ((krow & 7) << 3)));
      bf16x8 kbf = *(const bf16x8*)(Kl + ((krow*64 + 32 + g*8) ^ ((krow & 7) << 3)));
      sa = __builtin_amdgcn_mfma_f32_16x16x32_bf16(ka, qf0, sa, 0, 0, 0);
      sa = __builtin_amdgcn_mfma_f32_16x16x32_bf16(kbf, qf1, sa, 0, 0, 0);
      #pragma unroll
      for (int r = 0; r < 4; r++){
        const int keyg = kb + kf*16 + g*4 + r;
        float s = sa[r] * scale;
        const bool ok = (!diag) || (keyg < qrow);   // strict causal
        s = ok ? s : -1e30f;
        pv[kf*4 + r] = s;
        mt_ = fmaxf(mt_, s);
      }
    }
    mt_ = fmaxf(mt_, __shfl_xor(mt_, 16));
    mt_ = fmaxf(mt_, __shfl_xor(mt_, 32));
    const float mnew = fmaxf(mrun, mt_);
    const float alpha = __expf(mrun - mnew);
    short pr[16];
    float rs = 0.f;
    #pragma unroll
    for (int i2 = 0; i2 < 16; i2++){
      float p2 = (pv[i2] > -9e29f) ? __expf(pv[i2] - mnew) : 0.f;
      short pb = f2bf(p2);
      pr[i2] = pb;
      rs += bf2f(pb);            // denominator from rounded P (consistent with numerator)
    }
    rs += __shfl_xor(rs, 16);
    rs += __shfl_xor(rs, 32);
    lrun = lrun * alpha + rs;
    mrun = mnew;
    #pragma unroll
    for (int df = 0; df < 4; df++){
      accO[df][0] *= alpha; accO[df][1] *= alpha;
      accO[df][2] *= alpha; accO[df][3] *= alpha;
    }
    // P rows to per-wave LDS (b32 packed pairs; keys 4g+2rp consecutive)
    #pragma unroll
    for (int kf = 0; kf < 4; kf++){
      #pragma unroll
      for (int rp = 0; rp < 2; rp++){
        bf16x2 two;
        two[0] = pr[kf*4 + rp*2];
        two[1] = pr[kf*4 + rp*2 + 1];
        const int key = kf*16 + g*4 + rp*2;
        *(bf16x2*)(Pw + ((li*64 + key) ^ ((li & 7) << 3))) = two;
      }
    }
    // O^T += V^T @ P^T
    #pragma unroll
    for (int kc = 0; kc < 2; kc++){
      bf16x8 pf = *(const bf16x8*)(Pw + ((li*64 + kc*32 + g*8) ^ ((li & 7) << 3)));
      #pragma unroll
      for (int df = 0; df < 4; df++){
        const int dr = df*16 + li;
        bf16x8 vf = *(const bf16x8*)(Vt + ((dr*64 + kc*32 + g*8) ^ ((dr & 7) << 3)));
        accO[df] = __builtin_amdgcn_mfma_f32_16x16x32_bf16(vf, pf, accO[df], 0, 0, 0);
      }
    }
  }
  const float inv = (lrun > 0.f) ? (1.f / lrun) : 0.f;  // row 0: lrun==0 -> zeros (start_mask)
  #pragma unroll
  for (int df = 0; df < 4; df++){
    #pragma unroll
    for (int r = 0; r < 4; r++){
      const int d = df*16 + g*4 + r;
      out[((size_t)b*512 + nh*64 + d)*1024 + qrow] = accO[df][r] * inv;
    }
  }
}

extern "C" void kernel_launch(void* const* d_in, const int* in_sizes, int n_in,
                              void* d_out, int out_size, void* d_ws, size_t ws_size,
                              hipStream_t stream)
{
  (void)in_sizes; (void)n_in; (void)out_size; (void)ws_size;
  const float* query = (const float*)d_in[0];
  const float* key   = (const float*)d_in[1];
  const float* w1[3] = {(const float*)d_in[2],  (const float*)d_in[8],  (const float*)d_in[14]};
  const float* b1[3] = {(const float*)d_in[3],  (const float*)d_in[9],  (const float*)d_in[15]};
  const float* w2[3] = {(const float*)d_in[4],  (const float*)d_in[10], (const float*)d_in[16]};
  const float* b2[3] = {(const float*)d_in[5],  (const float*)d_in[11], (const float*)d_in[17]};
  const float* wn[3] = {(const float*)d_in[6],  (const float*)d_in[12], (const float*)d_in[18]};
  const float* bn[3] = {(const float*)d_in[7],  (const float*)d_in[13], (const float*)d_in[19]};

  char* ws = (char*)d_ws;
  short* wsW = (short*)(ws + OFF_W);
  short* tok = (short*)(ws + OFF_TOK);
  float* out = (float*)d_out;

  k_prep<<<dim3(960), dim3(256), 0, stream>>>(w1[0], w2[0], wn[0],
                                              w1[1], w2[1], wn[1],
                                              w1[2], w2[2], wn[2], wsW);
  k_branch<<<dim3(128, 3), dim3(256), 0, stream>>>(wsW, query, key,
                                                   b1[0], b1[1], b1[2],
                                                   b2[0], b2[1], b2[2],
                                                   bn[0], bn[1], bn[2], tok);
  k_attn<<<dim3(1024), dim3(256), 0, stream>>>(tok, out);
}

// Round 4
// 81.052 us; speedup vs baseline: 1.2642x; 1.2642x over previous
//
#include <hip/hip_runtime.h>
#include <cstdint>
#include <cstddef>

typedef __attribute__((ext_vector_type(4))) float f32x4;
typedef __attribute__((ext_vector_type(8))) short bf16x8;
typedef __attribute__((ext_vector_type(4))) short bf16x4;
typedef __attribute__((ext_vector_type(2))) short bf16x2;

#define DEVI static __device__ __forceinline__

DEVI short f2bf(float f){
  union { float f; uint32_t u; } v; v.f = f;
  uint32_t r = v.u + 0x7FFFu + ((v.u >> 16) & 1u);
  return (short)(r >> 16);
}
DEVI float bf2f(short h){
  union { uint32_t u; float f; } v; v.u = ((uint32_t)(uint16_t)h) << 16;
  return v.f;
}
DEVI float eluf(float x){ return x > 0.f ? x : (__expf(x) - 1.f); }
DEVI float sigm(float x){ return 1.f / (1.f + __expf(-x)); }

static constexpr int NPIX = 8 * 1024;   // B*S pixels

// ---- workspace layout (bytes) ----
static constexpr size_t SZ_W   = (size_t)983040 * 2;        // 3 x (w1 64K + w2 128K + wn 128K shorts)
static constexpr size_t SZ_ACT = (size_t)NPIX * 256 * 2;
static constexpr size_t OFF_W   = 0;
static constexpr size_t OFF_TOK = OFF_W + SZ_W + 8*SZ_ACT;  // 3 x (B,512,1024) bf16 flat

// ---------------- weight fp32 -> bf16 ----------------
__global__ void k_prep(const float* __restrict__ w1q, const float* __restrict__ w2q, const float* __restrict__ wnq,
                       const float* __restrict__ w1k, const float* __restrict__ w2k, const float* __restrict__ wnk,
                       const float* __restrict__ w1v, const float* __restrict__ w2v, const float* __restrict__ wnv,
                       short* __restrict__ dst)
{
  const float* s1[3] = {w1q, w1k, w1v};
  const float* s2[3] = {w2q, w2k, w2v};
  const float* s3[3] = {wnq, wnk, wnv};
  const int stride = gridDim.x * blockDim.x;
  for (int i = blockIdx.x * blockDim.x + threadIdx.x; i < 983040; i += stride){
    int br = i / 327680;
    int r  = i - br * 327680;
    float v;
    if (r < 65536)        v = s1[br][r];
    else if (r < 196608)  v = s2[br][r - 65536];
    else                  v = s3[br][r - 196608];
    dst[i] = f2bf(v);
  }
}

// ---------------- fused branch kernel, v2 ----------------
// One block = 64 tokens x one branch z; 4 waves, each wave owns 16 tokens
// end-to-end (B-operands in registers; h1/gr round-trip through WAVE-PRIVATE
// LDS -> no barriers for activations). W is shared block-wide through a
// double-buffered 32-row x 256-k LDS stage: 40 stages, ONE barrier each,
// next stage's global loads issued before the current stage's MFMA block
// (which covers the L2 latency). LDS = 2x16KB (W dbuf) + 4x8KB = 64 KB.
//
// Global stage numbering s = 0..39: 0-7 = W1 (8x32 rows), 8-23 = W2
// (mp 0..3, q 0..3: rows (q>=2?256:0)+mp*64+(q&1)*32), 24-39 = Wn.
DEVI const short* stage_ptr(const short* W1z, int s, int& r0){
  if (s < 8){ r0 = s << 5; return W1z; }
  if (s < 24){ int t = s - 8; r0 = ((t & 2) << 7) + ((t >> 2) << 6) + ((t & 1) << 5); return W1z + 65536; }
  int t = s - 24; r0 = t << 5; return W1z + 196608;
}

__global__ __launch_bounds__(256, 2)
void k_branch(const short* __restrict__ wsW,
              const float* __restrict__ query, const float* __restrict__ key,
              const float* __restrict__ b1q, const float* __restrict__ b1k, const float* __restrict__ b1v,
              const float* __restrict__ b2q, const float* __restrict__ b2k, const float* __restrict__ b2v,
              const float* __restrict__ bnq, const float* __restrict__ bnk, const float* __restrict__ bnv,
              short* __restrict__ tok)
{
  __shared__ short sW[2][8192];    // 2 x 32 rows x 256 k (16 KB each)
  __shared__ short sHG[4][4096];   // per-wave 16 tokens x 256 (h1, then gr overlay)

  const int z = blockIdx.y;
  const float* xin = (z == 0) ? query : key;
  const float* b1z = (z == 0) ? b1q : ((z == 1) ? b1k : b1v);
  const float* b2z = (z == 0) ? b2q : ((z == 1) ? b2k : b2v);
  const float* bnz = (z == 0) ? bnq : ((z == 1) ? bnk : bnv);
  const short* W1 = wsW + (size_t)z * 327680;
  short* tokz = tok + (size_t)z * NPIX * 512;

  const int tid = threadIdx.x, w = tid >> 6, g = (tid >> 4) & 3, li = tid & 15;
  const int gtok = blockIdx.x * 64 + w * 16;
  const int b = gtok >> 10, s0 = gtok & 1023;
  short* sHw = &sHG[w][0];
  const float* xb = xin + (size_t)b * 256 * 1024;

  // stage-issue / stage-write helpers (16 KB per stage, 4 x bf16x8 per thread)
  bf16x8 stg[4];
#define STAGE_ISSUE(SN)                                                         \
  { int r0_; const short* Wb_ = stage_ptr(W1, (SN), r0_);                       \
    _Pragma("unroll")                                                           \
    for (int it = 0; it < 4; it++){                                             \
      int gi = tid + it*256;                                                    \
      stg[it] = *(const bf16x8*)(Wb_ + (size_t)(r0_ + (gi >> 5))*256 + ((gi & 31) << 3)); } }
#define STAGE_WRITE(BUF)                                                        \
  { _Pragma("unroll")                                                           \
    for (int it = 0; it < 4; it++){                                             \
      int gi = tid + it*256; int row = gi >> 5;                                 \
      *(bf16x8*)((BUF) + row*256 + ((((gi & 31) ^ (row & 7))) << 3)) = stg[it]; } }

  // prologue: stage 0 into buf 0
  STAGE_ISSUE(0);
  STAGE_WRITE(sW[0]);

  // B-fragments for GEMM1: elu(x) loaded transpose-free from global.
  // lane (g,li) holds ex[k = ks*32+g*8+j][token s0+li], j=0..7.
  bf16x8 bB[8];
  #pragma unroll
  for (int ks = 0; ks < 8; ks++){
    #pragma unroll
    for (int j = 0; j < 8; j++){
      float e = xb[(size_t)(ks*32 + g*8 + j)*1024 + s0 + li];
      bB[ks][j] = f2bf(eluf(e));
    }
  }

  // ---- GEMM1: h1 = elu(W1 @ ex + b1) -> sHw[token][m] (8 stages) ----
  for (int s = 0; s < 8; s++){
    __syncthreads();
    STAGE_ISSUE(s + 1);
    const short* bufc = sW[s & 1];
    f32x4 acc[2] = {};
    #pragma unroll
    for (int mt = 0; mt < 2; mt++)
      #pragma unroll
      for (int ks = 0; ks < 8; ks++){
        bf16x8 afr = *(const bf16x8*)(bufc + (mt*16 + li)*256 + (((ks*4 + g) ^ (li & 7)) << 3));
        acc[mt] = __builtin_amdgcn_mfma_f32_16x16x32_bf16(afr, bB[ks], acc[mt], 0, 0, 0);
      }
    #pragma unroll
    for (int mt = 0; mt < 2; mt++){
      int m0 = s*32 + mt*16 + g*4;
      bf16x4 pk;
      #pragma unroll
      for (int r = 0; r < 4; r++)
        pk[r] = f2bf(eluf(acc[mt][r] + b1z[m0 + r]));
      *(bf16x4*)(sHw + li*256 + (m0 ^ ((li & 7) << 3))) = pk;
    }
    STAGE_WRITE(sW[(s + 1) & 1]);
  }

  // hoist all of h1 into registers (wave-private: no barrier needed)
  bf16x8 bH[8];
  #pragma unroll
  for (int ks = 0; ks < 8; ks++)
    bH[ks] = *(const bf16x8*)(sHw + li*256 + (((ks*4 + g) ^ (li & 7)) << 3));

  // ---- GEMM2: [a;g] = W2 @ h1 + b2 ; gr = x + a*sig(g) -> sHw overlay (16 stages) ----
  for (int mp = 0; mp < 4; mp++){
    f32x4 acc8[8] = {};
    #pragma unroll
    for (int q = 0; q < 4; q++){
      const int s = 8 + mp*4 + q;
      __syncthreads();
      STAGE_ISSUE(s + 1);
      const short* bufc = sW[s & 1];
      #pragma unroll
      for (int mt = 0; mt < 2; mt++)
        #pragma unroll
        for (int ks = 0; ks < 8; ks++){
          bf16x8 afr = *(const bf16x8*)(bufc + (mt*16 + li)*256 + (((ks*4 + g) ^ (li & 7)) << 3));
          acc8[q*2 + mt] = __builtin_amdgcn_mfma_f32_16x16x32_bf16(afr, bH[ks], acc8[q*2 + mt], 0, 0, 0);
        }
      STAGE_WRITE(sW[(s + 1) & 1]);
    }
    // epilogue for this mp: acc8[0..3] = a-half rows mp*64+mt*16, acc8[4..7] = g-half
    #pragma unroll
    for (int mt = 0; mt < 4; mt++){
      int m0 = mp*64 + mt*16 + g*4;
      bf16x4 pk;
      #pragma unroll
      for (int r = 0; r < 4; r++){
        float a  = acc8[mt][r] + b2z[m0 + r];
        float gg = acc8[4 + mt][r] + b2z[m0 + r + 256];
        float xv = xb[(size_t)(m0 + r)*1024 + s0 + li];
        pk[r] = f2bf(xv + a * sigm(gg));
      }
      *(bf16x4*)(sHw + li*256 + (m0 ^ ((li & 7) << 3))) = pk;
    }
  }

  // hoist gr into registers
  bf16x8 bG[8];
  #pragma unroll
  for (int ks = 0; ks < 8; ks++)
    bG[ks] = *(const bf16x8*)(sHw + li*256 + (((ks*4 + g) ^ (li & 7)) << 3));

  // ---- GEMM3: tok = Wn @ gr + bn -> global flat [b][512][1024] bf16 (16 stages) ----
  for (int s3 = 0; s3 < 16; s3++){
    const int s = 24 + s3;
    __syncthreads();
    const int sn = (s + 1 < 40) ? (s + 1) : 39;
    STAGE_ISSUE(sn);
    const short* bufc = sW[s & 1];
    f32x4 acc[2] = {};
    #pragma unroll
    for (int mt = 0; mt < 2; mt++)
      #pragma unroll
      for (int ks = 0; ks < 8; ks++){
        bf16x8 afr = *(const bf16x8*)(bufc + (mt*16 + li)*256 + (((ks*4 + g) ^ (li & 7)) << 3));
        acc[mt] = __builtin_amdgcn_mfma_f32_16x16x32_bf16(afr, bG[ks], acc[mt], 0, 0, 0);
      }
    #pragma unroll
    for (int mt = 0; mt < 2; mt++){
      #pragma unroll
      for (int r = 0; r < 4; r++){
        int m = s3*32 + mt*16 + g*4 + r;
        tokz[((size_t)b*512 + m)*1024 + s0 + li] = f2bf(acc[mt][r] + bnz[m]);
      }
    }
    STAGE_WRITE(sW[(s + 1) & 1]);
  }
#undef STAGE_ISSUE
#undef STAGE_WRITE
}

// ---------------- flash attention ----------------
// tok viewed as (B*1024 tokens, 512 feat) bf16; per (b, head): Q,K,V (1024 x 64).
// Strict causal (key < query), scale 1/sqrt(512), row 0 -> 0.
// Swapped QK^T: S^T = mfma(K, Q^T) so softmax state is lane-local.
// Grid = 1024 flat blocks; qt permuted so every stride-256 block family (one CU
// under XCD round-robin) has equal total work (perm stride-4 subsets sum to 30).
__global__ void k_attn(const short* __restrict__ tok, float* __restrict__ out)
{
  const short* qtok = tok;
  const short* ktok = tok + (size_t)NPIX * 512;
  const short* vtok = tok + (size_t)2 * NPIX * 512;
  const int flat = blockIdx.x;
  const int p = flat >> 6;
  const int g4 = p >> 2, r4 = p & 3;
  // perm = [15,14,13,12, 0,1,2,3, 11,10,9,8, 4,5,6,7]
  const int qt = (g4 == 0) ? (15 - r4) : (g4 == 1) ? r4 : (g4 == 2) ? (11 - r4) : (4 + r4);
  const int bh = flat & 63;
  const int b = bh >> 3, nh = bh & 7;
  const int tid = threadIdx.x, lane = tid & 63, w = tid >> 6, g = (tid >> 4) & 3, li = tid & 15;
  const int qrow = qt*64 + w*16 + li;       // this lane's query token
  __shared__ short Kl[64*64];
  __shared__ short Vt[64*64];               // V transposed: [d][k]
  __shared__ short Pl[4][1024];             // per-wave P [16 q][64 k]

  const short* qptr = qtok + ((size_t)(b*1024 + qrow))*512 + nh*64;
  bf16x8 qf0 = *(const bf16x8*)(qptr + g*8);
  bf16x8 qf1 = *(const bf16x8*)(qptr + 32 + g*8);

  f32x4 accO[4] = {};                       // O^T: 4 d-frags x (16d x 16q)
  float mrun = -1e30f, lrun = 0.f;
  const float scale = 0.04419417382415922f; // 1/sqrt(512)
  short* Pw = &Pl[w][0];

  for (int kt = 0; kt <= qt; kt++){
    const int kb = kt * 64;
    __syncthreads();
    #pragma unroll
    for (int it = 0; it < 2; it++){
      int i = tid + it*256;
      int kr = i >> 3, kc = i & 7;
      bf16x8 v = *(const bf16x8*)(ktok + ((size_t)(b*1024 + kb + kr))*512 + nh*64 + kc*8);
      *(bf16x8*)(Kl + ((kr*64 + kc*8) ^ ((kr & 7) << 3))) = v;
    }
    #pragma unroll
    for (int it = 0; it < 2; it++){
      int d0 = w*8 + it*32;                 // d uniform within wave -> conflict-free writes
      bf16x8 v = *(const bf16x8*)(vtok + ((size_t)(b*1024 + kb + lane))*512 + nh*64 + d0);
      #pragma unroll
      for (int j = 0; j < 8; j++){
        int d = d0 + j;
        Vt[(d*64 + lane) ^ ((d & 7) << 3)] = v[j];
      }
    }
    __syncthreads();

    // S^T frags: 4 x (16 keys x 16 q)
    float pv[16];
    float mt_ = -1e30f;
    const bool diag = (kt == qt);
    #pragma unroll
    for (int kf = 0; kf < 4; kf++){
      f32x4 sa = {};
      const int krow = kf*16 + li;
      bf16x8 ka  = *(const bf16x8*)(Kl + ((krow*64 + g*8) ^ ((krow & 7) << 3)));
      bf16x8 kbf = *(const bf16x8*)(Kl + ((krow*64 + 32 + g*8) ^ ((krow & 7) << 3)));
      sa = __builtin_amdgcn_mfma_f32_16x16x32_bf16(ka, qf0, sa, 0, 0, 0);
      sa = __builtin_amdgcn_mfma_f32_16x16x32_bf16(kbf, qf1, sa, 0, 0, 0);
      #pragma unroll
      for (int r = 0; r < 4; r++){
        const int keyg = kb + kf*16 + g*4 + r;
        float s = sa[r] * scale;
        const bool ok = (!diag) || (keyg < qrow);   // strict causal
        s = ok ? s : -1e30f;
        pv[kf*4 + r] = s;
        mt_ = fmaxf(mt_, s);
      }
    }
    mt_ = fmaxf(mt_, __shfl_xor(mt_, 16));
    mt_ = fmaxf(mt_, __shfl_xor(mt_, 32));
    const float mnew = fmaxf(mrun, mt_);
    const float alpha = __expf(mrun - mnew);
    short pr[16];
    float rs = 0.f;
    #pragma unroll
    for (int i2 = 0; i2 < 16; i2++){
      float p2 = (pv[i2] > -9e29f) ? __expf(pv[i2] - mnew) : 0.f;
      short pb = f2bf(p2);
      pr[i2] = pb;
      rs += bf2f(pb);            // denominator from rounded P (consistent with numerator)
    }
    rs += __shfl_xor(rs, 16);
    rs += __shfl_xor(rs, 32);
    lrun = lrun * alpha + rs;
    mrun = mnew;
    #pragma unroll
    for (int df = 0; df < 4; df++){
      accO[df][0] *= alpha; accO[df][1] *= alpha;
      accO[df][2] *= alpha; accO[df][3] *= alpha;
    }
    // P rows to per-wave LDS (b32 packed pairs; keys 4g+2rp consecutive)
    #pragma unroll
    for (int kf = 0; kf < 4; kf++){
      #pragma unroll
      for (int rp = 0; rp < 2; rp++){
        bf16x2 two;
        two[0] = pr[kf*4 + rp*2];
        two[1] = pr[kf*4 + rp*2 + 1];
        const int key = kf*16 + g*4 + rp*2;
        *(bf16x2*)(Pw + ((li*64 + key) ^ ((li & 7) << 3))) = two;
      }
    }
    // O^T += V^T @ P^T
    #pragma unroll
    for (int kc = 0; kc < 2; kc++){
      bf16x8 pf = *(const bf16x8*)(Pw + ((li*64 + kc*32 + g*8) ^ ((li & 7) << 3)));
      #pragma unroll
      for (int df = 0; df < 4; df++){
        const int dr = df*16 + li;
        bf16x8 vf = *(const bf16x8*)(Vt + ((dr*64 + kc*32 + g*8) ^ ((dr & 7) << 3)));
        accO[df] = __builtin_amdgcn_mfma_f32_16x16x32_bf16(vf, pf, accO[df], 0, 0, 0);
      }
    }
  }
  const float inv = (lrun > 0.f) ? (1.f / lrun) : 0.f;  // row 0: lrun==0 -> zeros (start_mask)
  #pragma unroll
  for (int df = 0; df < 4; df++){
    #pragma unroll
    for (int r = 0; r < 4; r++){
      const int d = df*16 + g*4 + r;
      out[((size_t)b*512 + nh*64 + d)*1024 + qrow] = accO[df][r] * inv;
    }
  }
}

extern "C" void kernel_launch(void* const* d_in, const int* in_sizes, int n_in,
                              void* d_out, int out_size, void* d_ws, size_t ws_size,
                              hipStream_t stream)
{
  (void)in_sizes; (void)n_in; (void)out_size; (void)ws_size;
  const float* query = (const float*)d_in[0];
  const float* key   = (const float*)d_in[1];
  const float* w1[3] = {(const float*)d_in[2],  (const float*)d_in[8],  (const float*)d_in[14]};
  const float* b1[3] = {(const float*)d_in[3],  (const float*)d_in[9],  (const float*)d_in[15]};
  const float* w2[3] = {(const float*)d_in[4],  (const float*)d_in[10], (const float*)d_in[16]};
  const float* b2[3] = {(const float*)d_in[5],  (const float*)d_in[11], (const float*)d_in[17]};
  const float* wn[3] = {(const float*)d_in[6],  (const float*)d_in[12], (const float*)d_in[18]};
  const float* bn[3] = {(const float*)d_in[7],  (const float*)d_in[13], (const float*)d_in[19]};

  char* ws = (char*)d_ws;
  short* wsW = (short*)(ws + OFF_W);
  short* tok = (short*)(ws + OFF_TOK);
  float* out = (float*)d_out;

  k_prep<<<dim3(960), dim3(256), 0, stream>>>(w1[0], w2[0], wn[0],
                                              w1[1], w2[1], wn[1],
                                              w1[2], w2[2], wn[2], wsW);
  k_branch<<<dim3(128, 3), dim3(256), 0, stream>>>(wsW, query, key,
                                                   b1[0], b1[1], b1[2],
                                                   b2[0], b2[1], b2[2],
                                                   bn[0], bn[1], bn[2], tok);
  k_attn<<<dim3(1024), dim3(256), 0, stream>>>(tok, out);
}